// Round 5
// baseline (390.911 us; speedup 1.0000x reference)
//
#include <hip/hip_runtime.h>
#include <hip/hip_bf16.h>

// Round 5: m97-style staging everywhere.
// - All GEMM/attention operands bf16; LDS tiles unpadded (128 B rows) filled
//   with __builtin_amdgcn_global_load_lds width=16 (async DMA, no VGPR trip).
// - pool1 unsplit with fused GELU; x pre-converted once; d_out's zf region
//   doubles as scratch for hbuf/ybuf/q2 (dead before L5 writes zf).
// - 7 launches: cvt, wt_all, L1(6 gemms), L2, L3, ATTN(4), L5(4).
// B=2, LF=2048, RATE=4, DF=1024, H=8, D2=512, hd=64, POOL_H=2048, TS=512.

typedef __attribute__((ext_vector_type(8))) short bf16x8;
typedef __attribute__((ext_vector_type(4))) float f32x4;
typedef unsigned short u16;
typedef unsigned int u32;

__device__ inline u16 f2bf(float f) {
    __hip_bfloat16 h = __float2bfloat16(f);
    return *reinterpret_cast<u16*>(&h);
}
__device__ inline u32 pack2(float a, float b) {
    return (u32)f2bf(a) | ((u32)f2bf(b) << 16);
}
__device__ inline void gld16(const u16* g, u16* l) {
    __builtin_amdgcn_global_load_lds(
        (const __attribute__((address_space(1))) void*)(g),
        (__attribute__((address_space(3))) void*)(l), 16, 0, 0);
}

// ---------------- multi-descriptor bf16 MFMA GEMM ----------------
// modes: 0 fp32+bias | 1 bf16+bias | 2 gelu+bf16 | 3 qkv split | 4 kv split
//        6 bf16+bias causal-shifted rows
struct GDesc {
    const u16* A; const u16* Bt; const float* bias;
    void* out0; u16* aux0; u16* aux1;
    int lda, ldb, ldc, K, ntx, mode, rshift, tile_end;
};
struct GPack { int n; int pad[3]; GDesc d[8]; };

template <int TMT>
__global__ __launch_bounds__(256)
void gemm_multi(GPack pk)
{
    constexpr int TM = TMT * 16;
    constexpr int W = TMT / 2;
    __shared__ u16 As[TM * 64];
    __shared__ u16 Bs[TM * 64];

    int bid = blockIdx.x;
    int di = 0;
    while (bid >= pk.d[di].tile_end) ++di;
    const GDesc g = pk.d[di];
    const int base = di ? pk.d[di - 1].tile_end : 0;
    const int local = bid - base;
    const int ty = local / g.ntx, tx = local - ty * g.ntx;
    const int row0 = ty * TM, col0 = tx * TM;

    const int t = threadIdx.x;
    const int wave = t >> 6, lane = t & 63;
    const int l15 = lane & 15, quad = lane >> 4;
    const int wm = (wave >> 1) * W * 16, wn = (wave & 1) * W * 16;

    // staging: lane covers row (wave*8 + lane/8), 16B chunk (lane%8)
    const int srow = wave * 8 + (lane >> 3);
    const int scol = (lane & 7) * 8;
    const u16* Ag = g.A + (long long)(row0 + srow) * g.lda + scol;
    const u16* Bg = g.Bt + (long long)(col0 + srow) * g.ldb + scol;

    f32x4 acc[W][W];
#pragma unroll
    for (int i = 0; i < W; ++i)
#pragma unroll
        for (int j = 0; j < W; ++j) {
            acc[i][j][0] = 0.f; acc[i][j][1] = 0.f;
            acc[i][j][2] = 0.f; acc[i][j][3] = 0.f;
        }

    for (int k0 = 0; k0 < g.K; k0 += 64) {
        __syncthreads();
#pragma unroll
        for (int r = 0; r < TM / 32; ++r) {
            gld16(Ag + (long long)r * 32 * g.lda + k0, As + r * 2048 + wave * 512);
            gld16(Bg + (long long)r * 32 * g.ldb + k0, Bs + r * 2048 + wave * 512);
        }
        __syncthreads();
#pragma unroll
        for (int kc = 0; kc < 2; ++kc) {
            bf16x8 af[W], bfr[W];
#pragma unroll
            for (int i = 0; i < W; ++i) {
                af[i]  = *(const bf16x8*)(As + (wm + i * 16 + l15) * 64 + kc * 32 + quad * 8);
                bfr[i] = *(const bf16x8*)(Bs + (wn + i * 16 + l15) * 64 + kc * 32 + quad * 8);
            }
#pragma unroll
            for (int i = 0; i < W; ++i)
#pragma unroll
                for (int j = 0; j < W; ++j)
                    acc[i][j] = __builtin_amdgcn_mfma_f32_16x16x32_bf16(af[i], bfr[j], acc[i][j], 0, 0, 0);
        }
    }

    const int rmask = (1 << g.rshift) - 1;
#pragma unroll
    for (int i = 0; i < W; ++i)
#pragma unroll
        for (int j = 0; j < W; ++j)
#pragma unroll
            for (int r = 0; r < 4; ++r) {
                int m = row0 + wm + i * 16 + quad * 4 + r;
                int n = col0 + wn + j * 16 + l15;
                float v = acc[i][j][r] + g.bias[n];
                if (g.mode == 0) {
                    ((float*)g.out0)[(long long)m * g.ldc + n] = v;
                } else if (g.mode == 1) {
                    ((u16*)g.out0)[(long long)m * g.ldc + n] = f2bf(v);
                } else if (g.mode == 2) {
                    float x3 = v * v * v;
                    v = 0.5f * v * (1.f + tanhf(0.7978845608028654f * (v + 0.044715f * x3)));
                    ((u16*)g.out0)[(long long)m * g.ldc + n] = f2bf(v);
                } else if (g.mode == 3) {
                    u16 h = f2bf(v);
                    if (n < 512) ((u16*)g.out0)[(long long)m * 512 + n] = h;
                    else if (n < 1024) g.aux0[(long long)m * 512 + (n - 512)] = h;
                    else {
                        int d = n - 1024;
                        int bb = m >> g.rshift, rr = m & rmask;
                        g.aux1[((long long)((bb * 8 + (d >> 6)) * 64 + (d & 63)) << g.rshift) + rr] = h;
                    }
                } else if (g.mode == 4) {
                    u16 h = f2bf(v);
                    if (n < 512) ((u16*)g.out0)[(long long)m * 512 + n] = h;
                    else {
                        int d = n - 512;
                        int bb = m >> g.rshift, rr = m & rmask;
                        g.aux1[((long long)((bb * 8 + (d >> 6)) * 64 + (d & 63)) << g.rshift) + rr] = h;
                    }
                } else {  // mode 6: causal shift fused
                    int t9 = m & 511;
                    if (t9 != 511) ((u16*)g.out0)[(long long)(m + 1) * g.ldc + n] = f2bf(v);
                    if (t9 == 0)  ((u16*)g.out0)[(long long)m * g.ldc + n] = 0;
                }
            }
}

// ---------------- multi-descriptor attention (no online max) ----------------
#define ALD 72

struct ADesc { const u16* Q; const u16* K; const u16* Vt; u16* O; int Rq, nk, tile_end, pad; };
struct APack { int n; int pad[3]; ADesc d[4]; };

__global__ __launch_bounds__(256)
void attn_multi(APack pk, float prescale)
{
    __shared__ u16 Qs[64 * 64];
    __shared__ u16 Ks[64 * 64];
    __shared__ u16 Vts[64 * 64];
    __shared__ u16 Ps[4][16 * ALD];

    int bid = blockIdx.x;
    int di = 0;
    while (bid >= pk.d[di].tile_end) ++di;
    const ADesc g = pk.d[di];
    const int base = di ? pk.d[di - 1].tile_end : 0;
    const int local = bid - base;

    const int t = threadIdx.x;
    const int wave = t >> 6, lane = t & 63;
    const int l15 = lane & 15, quad = lane >> 4;
    const int bh = local & 15, b = bh >> 3, h = bh & 7;
    const int q0 = (local >> 4) * 64;
    const int nk = g.nk;

    const int srow = wave * 8 + (lane >> 3);
    const int scol = (lane & 7) * 8;

    const u16* Qg = g.Q + ((long long)(b * g.Rq + q0 + srow) << 9) + h * 64 + scol;
    const u16* Kg = g.K + ((long long)(b * nk + srow) << 9) + h * 64 + scol;
    const u16* Vg = g.Vt + (long long)bh * 64 * nk + (long long)srow * nk + scol;

    // stage Q (64x64) via DMA
#pragma unroll
    for (int r = 0; r < 2; ++r)
        gld16(Qg + ((long long)r * 32 << 9), Qs + r * 2048 + wave * 512);
    __syncthreads();

    bf16x8 qf[2];
    qf[0] = *(const bf16x8*)(Qs + (wave * 16 + l15) * 64 + quad * 8);
    qf[1] = *(const bf16x8*)(Qs + (wave * 16 + l15) * 64 + 32 + quad * 8);

    f32x4 Oacc[4];
#pragma unroll
    for (int nt = 0; nt < 4; ++nt) { Oacc[nt][0] = 0.f; Oacc[nt][1] = 0.f; Oacc[nt][2] = 0.f; Oacc[nt][3] = 0.f; }
    float lr[4] = {0.f, 0.f, 0.f, 0.f};

    u16* Pw = &Ps[wave][0];

    for (int kt = 0; kt < nk; kt += 64) {
        __syncthreads();
#pragma unroll
        for (int r = 0; r < 2; ++r) {
            gld16(Kg + ((long long)(kt + r * 32) << 9), Ks + r * 2048 + wave * 512);
            gld16(Vg + (long long)r * 32 * nk + kt, Vts + r * 2048 + wave * 512);
        }
        __syncthreads();

#pragma unroll
        for (int k16 = 0; k16 < 4; ++k16) {
            f32x4 s;
            s[0] = 0.f; s[1] = 0.f; s[2] = 0.f; s[3] = 0.f;
            bf16x8 kf0 = *(const bf16x8*)(Ks + (k16 * 16 + l15) * 64 + quad * 8);
            bf16x8 kf1 = *(const bf16x8*)(Ks + (k16 * 16 + l15) * 64 + 32 + quad * 8);
            s = __builtin_amdgcn_mfma_f32_16x16x32_bf16(qf[0], kf0, s, 0, 0, 0);
            s = __builtin_amdgcn_mfma_f32_16x16x32_bf16(qf[1], kf1, s, 0, 0, 0);
#pragma unroll
            for (int r = 0; r < 4; ++r) {
                float p = exp2f(s[r] * prescale);
                lr[r] += p;
                Pw[(quad * 4 + r) * ALD + k16 * 16 + l15] = f2bf(p);
            }
        }

        bf16x8 pf0 = *(const bf16x8*)(Pw + l15 * ALD + quad * 8);
        bf16x8 pf1 = *(const bf16x8*)(Pw + l15 * ALD + 32 + quad * 8);
#pragma unroll
        for (int nt = 0; nt < 4; ++nt) {
            bf16x8 vf0 = *(const bf16x8*)(Vts + (nt * 16 + l15) * 64 + quad * 8);
            bf16x8 vf1 = *(const bf16x8*)(Vts + (nt * 16 + l15) * 64 + 32 + quad * 8);
            Oacc[nt] = __builtin_amdgcn_mfma_f32_16x16x32_bf16(pf0, vf0, Oacc[nt], 0, 0, 0);
            Oacc[nt] = __builtin_amdgcn_mfma_f32_16x16x32_bf16(pf1, vf1, Oacc[nt], 0, 0, 0);
        }
    }

    float inv[4];
#pragma unroll
    for (int r = 0; r < 4; ++r) {
        float s = lr[r];
#pragma unroll
        for (int off = 1; off < 16; off <<= 1) s += __shfl_xor(s, off);
        inv[r] = 1.f / s;
    }

    u16* Ob = g.O + ((long long)(b * g.Rq + q0 + wave * 16 + quad * 4) << 9) + h * 64;
#pragma unroll
    for (int nt = 0; nt < 4; ++nt)
#pragma unroll
        for (int r = 0; r < 4; ++r)
            Ob[(long long)r * 512 + nt * 16 + l15] = f2bf(Oacc[nt][r] * inv[r]);
}

// ---------------- multi weight transpose-convert ----------------
struct WDesc { const float* src; u16* dst; int ldn, K, tx_, tile_end; };
struct WPack { int n; int pad[3]; WDesc d[12]; };

__global__ __launch_bounds__(256)
void wt_multi(WPack pk)
{
    __shared__ float T[64][68];
    int bid = blockIdx.x;
    int di = 0;
    while (bid >= pk.d[di].tile_end) ++di;
    const WDesc g = pk.d[di];
    const int base = di ? pk.d[di - 1].tile_end : 0;
    const int local = bid - base;
    const int k0 = (local % g.tx_) * 64;
    const int n0 = (local / g.tx_) * 64;
    const int t = threadIdx.x;
#pragma unroll
    for (int i = 0; i < 4; ++i) {
        int idx = t + i * 256;
        int r = idx >> 4, c4 = idx & 15;
        float4 v = *(const float4*)(g.src + (long long)(k0 + r) * g.ldn + n0 + c4 * 4);
        T[r][c4 * 4 + 0] = v.x; T[r][c4 * 4 + 1] = v.y;
        T[r][c4 * 4 + 2] = v.z; T[r][c4 * 4 + 3] = v.w;
    }
    __syncthreads();
#pragma unroll
    for (int i = 0; i < 4; ++i) {
        int idx = t + i * 256;
        int rn = idx >> 4, k4 = idx & 15;
        uint2 u;
        u.x = pack2(T[k4 * 4 + 0][rn], T[k4 * 4 + 1][rn]);
        u.y = pack2(T[k4 * 4 + 2][rn], T[k4 * 4 + 3][rn]);
        *(uint2*)(g.dst + (long long)(n0 + rn) * g.K + k0 + k4 * 4) = u;
    }
}

// ---------------- fp32 -> bf16 (two tensors, one launch) ----------------
__global__ __launch_bounds__(256)
void c_cvt2(const float* __restrict__ a, u16* __restrict__ da, int na8,
            const float* __restrict__ b, u16* __restrict__ db)
{
    int i = blockIdx.x * 256 + threadIdx.x;
    const float* s; u16* d;
    if (i < na8) { s = a + (long long)i * 8; d = da + (long long)i * 8; }
    else { s = b + (long long)(i - na8) * 8; d = db + (long long)(i - na8) * 8; }
    float4 x = *(const float4*)s;
    float4 y = *(const float4*)(s + 4);
    uint4 u;
    u.x = pack2(x.x, x.y); u.y = pack2(x.z, x.w);
    u.z = pack2(y.x, y.y); u.w = pack2(y.z, y.w);
    *(uint4*)d = u;
}

// ---------------- launch ----------------
extern "C" void kernel_launch(void* const* d_in, const int* in_sizes, int n_in,
                              void* d_out, int out_size, void* d_ws, size_t ws_size,
                              hipStream_t stream)
{
    const float* x_fast      = (const float*)d_in[0];
    const float* x_slow      = (const float*)d_in[1];
    const float* fself_wqkv  = (const float*)d_in[2];
    const float* fself_bqkv  = (const float*)d_in[3];
    const float* fself_wo    = (const float*)d_in[4];
    const float* fself_bo    = (const float*)d_in[5];
    const float* fcross_wqkv = (const float*)d_in[6];
    const float* fcross_bqkv = (const float*)d_in[7];
    const float* fcross_wo   = (const float*)d_in[8];
    const float* fcross_bo   = (const float*)d_in[9];
    const float* sself_wqkv  = (const float*)d_in[10];
    const float* sself_bqkv  = (const float*)d_in[11];
    const float* sself_wo    = (const float*)d_in[12];
    const float* sself_bo    = (const float*)d_in[13];
    const float* scross_wqkv = (const float*)d_in[14];
    const float* scross_bqkv = (const float*)d_in[15];
    const float* scross_wo   = (const float*)d_in[16];
    const float* scross_bo   = (const float*)d_in[17];
    const float* lift_w      = (const float*)d_in[18];
    const float* lift_b      = (const float*)d_in[19];
    const float* pool_w1     = (const float*)d_in[20];
    const float* pool_b1     = (const float*)d_in[21];
    const float* pool_w2     = (const float*)d_in[22];
    const float* pool_b2     = (const float*)d_in[23];

    float* out = (float*)d_out;
    float* zf = out;                       // (2,2048,1024) fp32
    float* zs = out + 2LL * 2048 * 1024;   // (2,512,1024) fp32

    float* ws = (float*)d_ws;
    // ---- ws arena (fl offsets; peak 13,893,632 < 14,155,776 proven) ----
    u16* pw1T     = (u16*)(ws + 0);          // 4,194,304 fl (dead after L1)
    u16* wqkvT_f  = (u16*)(ws + 4194304);    // 393,216 fl each
    u16* wqkvT_c  = (u16*)(ws + 4587520);
    u16* wqkvT_s  = (u16*)(ws + 4980736);
    u16* wqkvT_sc = (u16*)(ws + 5373952);
    u16* liftT    = (u16*)(ws + 5767168);    // 262,144
    u16* pw2T     = (u16*)(ws + 6029312);    // 524,288
    u16* woT_f    = (u16*)(ws + 6553600);    // 131,072 each
    u16* woT_c    = (u16*)(ws + 6684672);
    u16* woT_s    = (u16*)(ws + 6815744);
    u16* woT_sc   = (u16*)(ws + 6946816);
    u16* xfb      = (u16*)(ws + 7077888);    // 2,097,152 fl (dead after L1)
    u16* xsb      = (u16*)(ws + 9175040);    // 524,288
    u16* q1       = (u16*)(ws + 9699328);    // 1,048,576 fl each
    u16* k1       = (u16*)(ws + 10747904);
    u16* vt1      = (u16*)(ws + 11796480);
    u16* qs       = (u16*)(ws + 12845056);   // 262,144 fl each
    u16* ks       = (u16*)(ws + 13107200);
    u16* vts      = (u16*)(ws + 13369344);
    u16* qcs      = (u16*)(ws + 13631488);   // ends 13,893,632
    // reuse of dead pw1T region after L1:
    u16* k2    = (u16*)(ws + 0);             // 262,144 fl
    u16* vt2   = (u16*)(ws + 262144);
    u16* sbufS = (u16*)(ws + 524288);
    u16* kcs   = (u16*)(ws + 786432);
    u16* vtcs  = (u16*)(ws + 1048576);
    u16* fo1   = (u16*)(ws + 1310720);       // 1,048,576 fl
    u16* fo2   = (u16*)(ws + 2359296);
    u16* so1   = (u16*)(ws + 3407872);       // 262,144 fl
    u16* so2   = (u16*)(ws + 3670016);       // ends 3,932,160
    // d_out zf region as scratch (dead before L5 writes zf):
    u16* q2   = (u16*)(out + 0);             // 1,048,576 fl
    u16* ybuf = (u16*)(out + 1048576);       // 262,144 fl
    u16* hbuf = (u16*)(out + 1310720);       // 1,048,576 fl (ends 2,359,296 < zf end)

    // ---- cvt: x_fast, x_slow -> bf16 ----
    hipLaunchKernelGGL(c_cvt2, dim3(2560), dim3(256), 0, stream,
                       x_fast, xfb, 524288, x_slow, xsb);

    // ---- wt_all: every weight transpose-convert, one launch ----
    {
        WPack p; p.n = 11;
        int te = 0, i = 0;
        auto add = [&](const float* s, u16* d, int ldn, int K, int N) {
            te += (K / 64) * (N / 64);
            p.d[i++] = WDesc{s, d, ldn, K, K / 64, te};
        };
        add(pool_w1, pw1T, 2048, 4096, 2048);
        add(fself_wqkv, wqkvT_f, 1536, 512, 1536);
        add(fcross_wqkv, wqkvT_c, 1536, 512, 1536);
        add(sself_wqkv, wqkvT_s, 1536, 512, 1536);
        add(scross_wqkv, wqkvT_sc, 1536, 512, 1536);
        add(lift_w, liftT, 512, 1024, 512);
        add(pool_w2, pw2T, 512, 2048, 512);
        add(fself_wo, woT_f, 512, 512, 512);
        add(fcross_wo, woT_c, 512, 512, 512);
        add(sself_wo, woT_s, 512, 512, 512);
        add(scross_wo, woT_sc, 512, 512, 512);
        hipLaunchKernelGGL(wt_multi, dim3(te), dim3(256), 0, stream, p);
    }

    auto gl = [&](GPack& p, int i, const u16* A, int lda,
                  const u16* Bt, int ldb, const float* bias,
                  void* out0, int ldc, int M, int N, int K, int mode,
                  u16* aux0, u16* aux1, int rshift, int TM, int& te) {
        te += (M / TM) * (N / TM);
        p.d[i] = GDesc{A, Bt, bias, out0, aux0, aux1,
                       lda, ldb, ldc, K, N / TM, mode, rshift, te};
    };

    // ---- L1: all input-side GEMMs (heavy pool1 first for load balance) ----
    {
        GPack p; p.n = 6; int te = 0;
        gl(p, 0, xfb, 4096, pw1T, 4096, pool_b1, hbuf, 2048,
           1024, 2048, 4096, 2, 0, 0, 0, 128, te);                    // pool1+gelu
        gl(p, 1, xfb, 1024, wqkvT_f, 512, fself_bqkv, q1, 512,
           4096, 1536, 512, 3, k1, vt1, 11, 128, te);                 // fself qkv
        gl(p, 2, xfb + 512, 1024, wqkvT_c, 512, fcross_bqkv, q2, 512,
           4096, 512, 512, 1, 0, 0, 0, 128, te);                      // fcross q
        gl(p, 3, xsb, 1024, wqkvT_s, 512, sself_bqkv, qs, 512,
           1024, 1536, 512, 3, ks, vts, 9, 128, te);                  // sself qkv
        gl(p, 4, xsb, 1024, liftT, 1024, lift_b, ybuf, 512,
           1024, 512, 1024, 1, 0, 0, 0, 128, te);                     // lift
        gl(p, 5, xsb + 512, 1024, wqkvT_sc, 512, scross_bqkv, qcs, 512,
           1024, 512, 512, 1, 0, 0, 0, 128, te);                      // scross q
        hipLaunchKernelGGL(gemm_multi<8>, dim3(te), dim3(256), 0, stream, p);
    }

    // ---- L2 (64-tiles): fcross kv + pool2(shift-fused) ----
    {
        GPack p; p.n = 2; int te = 0;
        gl(p, 0, ybuf, 512, wqkvT_c + 512 * 512, 512, fcross_bqkv + 512, k2, 512,
           1024, 1024, 512, 4, 0, vt2, 9, 64, te);
        gl(p, 1, hbuf, 2048, pw2T, 2048, pool_b2, sbufS, 512,
           1024, 512, 2048, 6, 0, 0, 0, 64, te);
        hipLaunchKernelGGL(gemm_multi<4>, dim3(te), dim3(256), 0, stream, p);
    }

    // ---- L3 (64-tiles): scross kv ----
    {
        GPack p; p.n = 1; int te = 0;
        gl(p, 0, sbufS, 512, wqkvT_sc + 512 * 512, 512, scross_bqkv + 512, kcs, 512,
           1024, 1024, 512, 4, 0, vtcs, 9, 64, te);
        hipLaunchKernelGGL(gemm_multi<4>, dim3(te), dim3(256), 0, stream, p);
    }

    // ---- ATTN: all four attentions ----
    {
        APack p; p.n = 4;
        int te = 0, i = 0;
        auto add = [&](const u16* Q, const u16* K, const u16* Vt, u16* O, int Rq, int nk) {
            te += (Rq / 64) * 16;
            p.d[i++] = ADesc{Q, K, Vt, O, Rq, nk, te, 0};
        };
        add(q1, k1, vt1, fo1, 2048, 2048);   // fself
        add(q2, k2, vt2, fo2, 2048, 512);    // fcross (repeat cancels in softmax)
        add(qs, ks, vts, so1, 512, 512);     // sself
        add(qcs, kcs, vtcs, so2, 512, 512);  // scross
        hipLaunchKernelGGL(attn_multi, dim3(te), dim3(256), 0, stream, p,
                           0.125f * 1.4426950408889634f);
    }

    // ---- L5: all four out-projections (fp32 into d_out) ----
    {
        GPack p; p.n = 4; int te = 0;
        gl(p, 0, fo1, 512, woT_f, 512, fself_bo, zf, 1024,
           4096, 512, 512, 0, 0, 0, 0, 128, te);
        gl(p, 1, fo2, 512, woT_c, 512, fcross_bo, zf + 512, 1024,
           4096, 512, 512, 0, 0, 0, 0, 128, te);
        gl(p, 2, so1, 512, woT_s, 512, sself_bo, zs, 1024,
           1024, 512, 512, 0, 0, 0, 0, 128, te);
        gl(p, 3, so2, 512, woT_sc, 512, scross_bo, zs + 512, 1024,
           1024, 512, 512, 0, 0, 0, 0, 128, te);
        hipLaunchKernelGGL(gemm_multi<8>, dim3(te), dim3(256), 0, stream, p);
    }
}

// Round 6
// 374.088 us; speedup vs baseline: 1.0450x; 1.0450x over previous
//
#include <hip/hip_runtime.h>
#include <hip/hip_bf16.h>

// Round 6: r5 + XOR chunk swizzle on all DMA-staged LDS tiles (kills the
// 10.6M bank conflicts the unpadded 128-B rows caused) + pool1 split-K=2
// for L1 load balance (r4-proven). 8 launches.
// B=2, LF=2048, RATE=4, DF=1024, H=8, D2=512, hd=64, POOL_H=2048, TS=512.

typedef __attribute__((ext_vector_type(8))) short bf16x8;
typedef __attribute__((ext_vector_type(4))) float f32x4;
typedef unsigned short u16;
typedef unsigned int u32;

__device__ inline u16 f2bf(float f) {
    __hip_bfloat16 h = __float2bfloat16(f);
    return *reinterpret_cast<u16*>(&h);
}
__device__ inline u32 pack2(float a, float b) {
    return (u32)f2bf(a) | ((u32)f2bf(b) << 16);
}
__device__ inline float bf2f(u16 h) {
    u32 x = ((u32)h) << 16; float f;
    __builtin_memcpy(&f, &x, 4);
    return f;
}
__device__ inline void gld16(const u16* g, u16* l) {
    __builtin_amdgcn_global_load_lds(
        (const __attribute__((address_space(1))) void*)(g),
        (__attribute__((address_space(3))) void*)(l), 16, 0, 0);
}

// ---------------- multi-descriptor bf16 MFMA GEMM ----------------
// modes: 0 fp32+bias | 1 bf16+bias | 2 gelu+bf16 | 3 qkv split | 4 kv split
//        5 bf16 partial (no bias) | 6 bf16+bias causal-shifted rows
// LDS rows are 64 u16 (128 B), chunk-swizzled: LDS[R][c] = glob[R][c^(R&7)].
struct GDesc {
    const u16* A; const u16* Bt; const float* bias;
    void* out0; u16* aux0; u16* aux1;
    int lda, ldb, ldc, K, ntx, mode, rshift, tile_end;
};
struct GPack { int n; int pad[3]; GDesc d[8]; };

template <int TMT>
__global__ __launch_bounds__(256)
void gemm_multi(GPack pk)
{
    constexpr int TM = TMT * 16;
    constexpr int W = TMT / 2;
    __shared__ u16 As[TM * 64];
    __shared__ u16 Bs[TM * 64];

    int bid = blockIdx.x;
    int di = 0;
    while (bid >= pk.d[di].tile_end) ++di;
    const GDesc g = pk.d[di];
    const int base = di ? pk.d[di - 1].tile_end : 0;
    const int local = bid - base;
    const int ty = local / g.ntx, tx = local - ty * g.ntx;
    const int row0 = ty * TM, col0 = tx * TM;

    const int t = threadIdx.x;
    const int wave = t >> 6, lane = t & 63;
    const int l15 = lane & 15, quad = lane >> 4;
    const int wm = (wave >> 1) * W * 16, wn = (wave & 1) * W * 16;

    // staging: lane covers row (wave*8 + lane/8); global chunk XOR-swizzled
    const int srow = wave * 8 + (lane >> 3);
    const int ssw = (((lane & 7) ^ (lane >> 3))) * 8;
    const u16* Ag = g.A + (long long)(row0 + srow) * g.lda + ssw;
    const u16* Bg = g.Bt + (long long)(col0 + srow) * g.ldb + ssw;

    // fragment-read swizzled chunk offset (u16): kc=0 -> c0, kc=1 -> c0^32
    const int c0 = (quad ^ (l15 & 7)) * 8;

    f32x4 acc[W][W];
#pragma unroll
    for (int i = 0; i < W; ++i)
#pragma unroll
        for (int j = 0; j < W; ++j) {
            acc[i][j][0] = 0.f; acc[i][j][1] = 0.f;
            acc[i][j][2] = 0.f; acc[i][j][3] = 0.f;
        }

    for (int k0 = 0; k0 < g.K; k0 += 64) {
        __syncthreads();
#pragma unroll
        for (int r = 0; r < TM / 32; ++r) {
            gld16(Ag + (long long)r * 32 * g.lda + k0, As + r * 2048 + wave * 512);
            gld16(Bg + (long long)r * 32 * g.ldb + k0, Bs + r * 2048 + wave * 512);
        }
        __syncthreads();
#pragma unroll
        for (int kc = 0; kc < 2; ++kc) {
            const int cc = kc ? (c0 ^ 32) : c0;
            bf16x8 af[W], bfr[W];
#pragma unroll
            for (int i = 0; i < W; ++i) {
                af[i]  = *(const bf16x8*)(As + (wm + i * 16 + l15) * 64 + cc);
                bfr[i] = *(const bf16x8*)(Bs + (wn + i * 16 + l15) * 64 + cc);
            }
#pragma unroll
            for (int i = 0; i < W; ++i)
#pragma unroll
                for (int j = 0; j < W; ++j)
                    acc[i][j] = __builtin_amdgcn_mfma_f32_16x16x32_bf16(af[i], bfr[j], acc[i][j], 0, 0, 0);
        }
    }

    const int rmask = (1 << g.rshift) - 1;
#pragma unroll
    for (int i = 0; i < W; ++i)
#pragma unroll
        for (int j = 0; j < W; ++j)
#pragma unroll
            for (int r = 0; r < 4; ++r) {
                int m = row0 + wm + i * 16 + quad * 4 + r;
                int n = col0 + wn + j * 16 + l15;
                float v = acc[i][j][r];
                if (g.mode != 5) v += g.bias[n];
                if (g.mode == 0) {
                    ((float*)g.out0)[(long long)m * g.ldc + n] = v;
                } else if (g.mode == 1 || g.mode == 5) {
                    ((u16*)g.out0)[(long long)m * g.ldc + n] = f2bf(v);
                } else if (g.mode == 2) {
                    float x3 = v * v * v;
                    v = 0.5f * v * (1.f + tanhf(0.7978845608028654f * (v + 0.044715f * x3)));
                    ((u16*)g.out0)[(long long)m * g.ldc + n] = f2bf(v);
                } else if (g.mode == 3) {
                    u16 h = f2bf(v);
                    if (n < 512) ((u16*)g.out0)[(long long)m * 512 + n] = h;
                    else if (n < 1024) g.aux0[(long long)m * 512 + (n - 512)] = h;
                    else {
                        int d = n - 1024;
                        int bb = m >> g.rshift, rr = m & rmask;
                        g.aux1[((long long)((bb * 8 + (d >> 6)) * 64 + (d & 63)) << g.rshift) + rr] = h;
                    }
                } else if (g.mode == 4) {
                    u16 h = f2bf(v);
                    if (n < 512) ((u16*)g.out0)[(long long)m * 512 + n] = h;
                    else {
                        int d = n - 512;
                        int bb = m >> g.rshift, rr = m & rmask;
                        g.aux1[((long long)((bb * 8 + (d >> 6)) * 64 + (d & 63)) << g.rshift) + rr] = h;
                    }
                } else {  // mode 6: causal shift fused
                    int t9 = m & 511;
                    if (t9 != 511) ((u16*)g.out0)[(long long)(m + 1) * g.ldc + n] = f2bf(v);
                    if (t9 == 0)  ((u16*)g.out0)[(long long)m * g.ldc + n] = 0;
                }
            }
}

// ---------------- multi-descriptor attention (no online max) ----------------
#define ALD 72

struct ADesc { const u16* Q; const u16* K; const u16* Vt; u16* O; int Rq, nk, tile_end, pad; };
struct APack { int n; int pad[3]; ADesc d[4]; };

__global__ __launch_bounds__(256)
void attn_multi(APack pk, float prescale)
{
    __shared__ u16 Qs[64 * 64];
    __shared__ u16 Ks[64 * 64];
    __shared__ u16 Vts[64 * 64];
    __shared__ u16 Ps[4][16 * ALD];

    int bid = blockIdx.x;
    int di = 0;
    while (bid >= pk.d[di].tile_end) ++di;
    const ADesc g = pk.d[di];
    const int base = di ? pk.d[di - 1].tile_end : 0;
    const int local = bid - base;

    const int t = threadIdx.x;
    const int wave = t >> 6, lane = t & 63;
    const int l15 = lane & 15, quad = lane >> 4;
    const int bh = local & 15, b = bh >> 3, h = bh & 7;
    const int q0 = (local >> 4) * 64;
    const int nk = g.nk;

    const int srow = wave * 8 + (lane >> 3);
    const int ssw = (((lane & 7) ^ (lane >> 3))) * 8;
    const int c0 = (quad ^ (l15 & 7)) * 8;

    const u16* Qg = g.Q + ((long long)(b * g.Rq + q0 + srow) << 9) + h * 64 + ssw;
    const u16* Kg = g.K + ((long long)(b * nk + srow) << 9) + h * 64 + ssw;
    const u16* Vg = g.Vt + (long long)bh * 64 * nk + (long long)srow * nk + ssw;

#pragma unroll
    for (int r = 0; r < 2; ++r)
        gld16(Qg + ((long long)r * 32 << 9), Qs + r * 2048 + wave * 512);
    __syncthreads();

    bf16x8 qf[2];
    qf[0] = *(const bf16x8*)(Qs + (wave * 16 + l15) * 64 + c0);
    qf[1] = *(const bf16x8*)(Qs + (wave * 16 + l15) * 64 + (c0 ^ 32));

    f32x4 Oacc[4];
#pragma unroll
    for (int nt = 0; nt < 4; ++nt) { Oacc[nt][0] = 0.f; Oacc[nt][1] = 0.f; Oacc[nt][2] = 0.f; Oacc[nt][3] = 0.f; }
    float lr[4] = {0.f, 0.f, 0.f, 0.f};

    u16* Pw = &Ps[wave][0];

    for (int kt = 0; kt < nk; kt += 64) {
        __syncthreads();
#pragma unroll
        for (int r = 0; r < 2; ++r) {
            gld16(Kg + ((long long)(kt + r * 32) << 9), Ks + r * 2048 + wave * 512);
            gld16(Vg + (long long)r * 32 * nk + kt, Vts + r * 2048 + wave * 512);
        }
        __syncthreads();

#pragma unroll
        for (int k16 = 0; k16 < 4; ++k16) {
            f32x4 s;
            s[0] = 0.f; s[1] = 0.f; s[2] = 0.f; s[3] = 0.f;
            bf16x8 kf0 = *(const bf16x8*)(Ks + (k16 * 16 + l15) * 64 + c0);
            bf16x8 kf1 = *(const bf16x8*)(Ks + (k16 * 16 + l15) * 64 + (c0 ^ 32));
            s = __builtin_amdgcn_mfma_f32_16x16x32_bf16(qf[0], kf0, s, 0, 0, 0);
            s = __builtin_amdgcn_mfma_f32_16x16x32_bf16(qf[1], kf1, s, 0, 0, 0);
#pragma unroll
            for (int r = 0; r < 4; ++r) {
                float p = exp2f(s[r] * prescale);
                lr[r] += p;
                Pw[(quad * 4 + r) * ALD + k16 * 16 + l15] = f2bf(p);
            }
        }

        bf16x8 pf0 = *(const bf16x8*)(Pw + l15 * ALD + quad * 8);
        bf16x8 pf1 = *(const bf16x8*)(Pw + l15 * ALD + 32 + quad * 8);
#pragma unroll
        for (int nt = 0; nt < 4; ++nt) {
            bf16x8 vf0 = *(const bf16x8*)(Vts + (nt * 16 + l15) * 64 + c0);
            bf16x8 vf1 = *(const bf16x8*)(Vts + (nt * 16 + l15) * 64 + (c0 ^ 32));
            Oacc[nt] = __builtin_amdgcn_mfma_f32_16x16x32_bf16(pf0, vf0, Oacc[nt], 0, 0, 0);
            Oacc[nt] = __builtin_amdgcn_mfma_f32_16x16x32_bf16(pf1, vf1, Oacc[nt], 0, 0, 0);
        }
    }

    float inv[4];
#pragma unroll
    for (int r = 0; r < 4; ++r) {
        float s = lr[r];
#pragma unroll
        for (int off = 1; off < 16; off <<= 1) s += __shfl_xor(s, off);
        inv[r] = 1.f / s;
    }

    u16* Ob = g.O + ((long long)(b * g.Rq + q0 + wave * 16 + quad * 4) << 9) + h * 64;
#pragma unroll
    for (int nt = 0; nt < 4; ++nt)
#pragma unroll
        for (int r = 0; r < 4; ++r)
            Ob[(long long)r * 512 + nt * 16 + l15] = f2bf(Oacc[nt][r] * inv[r]);
}

// ---------------- multi weight transpose-convert ----------------
struct WDesc { const float* src; u16* dst; int ldn, K, tx_, tile_end; };
struct WPack { int n; int pad[3]; WDesc d[12]; };

__global__ __launch_bounds__(256)
void wt_multi(WPack pk)
{
    __shared__ float T[64][68];
    int bid = blockIdx.x;
    int di = 0;
    while (bid >= pk.d[di].tile_end) ++di;
    const WDesc g = pk.d[di];
    const int base = di ? pk.d[di - 1].tile_end : 0;
    const int local = bid - base;
    const int k0 = (local % g.tx_) * 64;
    const int n0 = (local / g.tx_) * 64;
    const int t = threadIdx.x;
#pragma unroll
    for (int i = 0; i < 4; ++i) {
        int idx = t + i * 256;
        int r = idx >> 4, c4 = idx & 15;
        float4 v = *(const float4*)(g.src + (long long)(k0 + r) * g.ldn + n0 + c4 * 4);
        T[r][c4 * 4 + 0] = v.x; T[r][c4 * 4 + 1] = v.y;
        T[r][c4 * 4 + 2] = v.z; T[r][c4 * 4 + 3] = v.w;
    }
    __syncthreads();
#pragma unroll
    for (int i = 0; i < 4; ++i) {
        int idx = t + i * 256;
        int rn = idx >> 4, k4 = idx & 15;
        uint2 u;
        u.x = pack2(T[k4 * 4 + 0][rn], T[k4 * 4 + 1][rn]);
        u.y = pack2(T[k4 * 4 + 2][rn], T[k4 * 4 + 3][rn]);
        *(uint2*)(g.dst + (long long)(n0 + rn) * g.K + k0 + k4 * 4) = u;
    }
}

// ---------------- fp32 -> bf16 (two tensors, one launch) ----------------
__global__ __launch_bounds__(256)
void c_cvt2(const float* __restrict__ a, u16* __restrict__ da, int na8,
            const float* __restrict__ b, u16* __restrict__ db)
{
    int i = blockIdx.x * 256 + threadIdx.x;
    const float* s; u16* d;
    if (i < na8) { s = a + (long long)i * 8; d = da + (long long)i * 8; }
    else { s = b + (long long)(i - na8) * 8; d = db + (long long)(i - na8) * 8; }
    float4 x = *(const float4*)s;
    float4 y = *(const float4*)(s + 4);
    uint4 u;
    u.x = pack2(x.x, x.y); u.y = pack2(x.z, x.w);
    u.z = pack2(y.x, y.y); u.w = pack2(y.z, y.w);
    *(uint4*)d = u;
}

// ---------------- pool1 partial combine + bias + gelu (in place on p0) ----
__global__ __launch_bounds__(256)
void gelu_sum(u16* __restrict__ p0, const u16* __restrict__ p1,
              const float* __restrict__ bias)
{
    int i8 = (blockIdx.x * 256 + threadIdx.x) * 8;   // over 1024*2048 elems
    uint4 a = *(const uint4*)(p0 + i8);
    uint4 b = *(const uint4*)(p1 + i8);
    int n = i8 & 2047;
    float4 bi0 = *(const float4*)(bias + n);
    float4 bi1 = *(const float4*)(bias + n + 4);
    float bb[8] = {bi0.x, bi0.y, bi0.z, bi0.w, bi1.x, bi1.y, bi1.z, bi1.w};
    u32 aw[4] = {a.x, a.y, a.z, a.w};
    u32 bw[4] = {b.x, b.y, b.z, b.w};
    u32 ow[4];
#pragma unroll
    for (int k = 0; k < 4; ++k) {
        float v0 = bf2f((u16)(aw[k] & 0xffff)) + bf2f((u16)(bw[k] & 0xffff)) + bb[2 * k];
        float v1 = bf2f((u16)(aw[k] >> 16)) + bf2f((u16)(bw[k] >> 16)) + bb[2 * k + 1];
        float x3 = v0 * v0 * v0;
        v0 = 0.5f * v0 * (1.f + tanhf(0.7978845608028654f * (v0 + 0.044715f * x3)));
        x3 = v1 * v1 * v1;
        v1 = 0.5f * v1 * (1.f + tanhf(0.7978845608028654f * (v1 + 0.044715f * x3)));
        ow[k] = pack2(v0, v1);
    }
    uint4 o; o.x = ow[0]; o.y = ow[1]; o.z = ow[2]; o.w = ow[3];
    *(uint4*)(p0 + i8) = o;
}

// ---------------- launch ----------------
extern "C" void kernel_launch(void* const* d_in, const int* in_sizes, int n_in,
                              void* d_out, int out_size, void* d_ws, size_t ws_size,
                              hipStream_t stream)
{
    const float* x_fast      = (const float*)d_in[0];
    const float* x_slow      = (const float*)d_in[1];
    const float* fself_wqkv  = (const float*)d_in[2];
    const float* fself_bqkv  = (const float*)d_in[3];
    const float* fself_wo    = (const float*)d_in[4];
    const float* fself_bo    = (const float*)d_in[5];
    const float* fcross_wqkv = (const float*)d_in[6];
    const float* fcross_bqkv = (const float*)d_in[7];
    const float* fcross_wo   = (const float*)d_in[8];
    const float* fcross_bo   = (const float*)d_in[9];
    const float* sself_wqkv  = (const float*)d_in[10];
    const float* sself_bqkv  = (const float*)d_in[11];
    const float* sself_wo    = (const float*)d_in[12];
    const float* sself_bo    = (const float*)d_in[13];
    const float* scross_wqkv = (const float*)d_in[14];
    const float* scross_bqkv = (const float*)d_in[15];
    const float* scross_wo   = (const float*)d_in[16];
    const float* scross_bo   = (const float*)d_in[17];
    const float* lift_w      = (const float*)d_in[18];
    const float* lift_b      = (const float*)d_in[19];
    const float* pool_w1     = (const float*)d_in[20];
    const float* pool_b1     = (const float*)d_in[21];
    const float* pool_w2     = (const float*)d_in[22];
    const float* pool_b2     = (const float*)d_in[23];

    float* out = (float*)d_out;
    float* zf = out;                       // (2,2048,1024) fp32
    float* zs = out + 2LL * 2048 * 1024;   // (2,512,1024) fp32

    float* ws = (float*)d_ws;
    // ---- ws arena (fl offsets; peak 13,893,632 < 14,155,776 proven) ----
    u16* pw1T     = (u16*)(ws + 0);          // 4,194,304 fl (dead after L1)
    u16* wqkvT_f  = (u16*)(ws + 4194304);
    u16* wqkvT_c  = (u16*)(ws + 4587520);
    u16* wqkvT_s  = (u16*)(ws + 4980736);
    u16* wqkvT_sc = (u16*)(ws + 5373952);
    u16* liftT    = (u16*)(ws + 5767168);
    u16* pw2T     = (u16*)(ws + 6029312);
    u16* woT_f    = (u16*)(ws + 6553600);
    u16* woT_c    = (u16*)(ws + 6684672);
    u16* woT_s    = (u16*)(ws + 6815744);
    u16* woT_sc   = (u16*)(ws + 6946816);
    u16* xfb      = (u16*)(ws + 7077888);    // 2,097,152 fl (dead after L1)
    u16* xsb      = (u16*)(ws + 9175040);
    u16* q1       = (u16*)(ws + 9699328);    // 1,048,576 fl each
    u16* k1       = (u16*)(ws + 10747904);
    u16* vt1      = (u16*)(ws + 11796480);
    u16* qs       = (u16*)(ws + 12845056);   // 262,144 fl each
    u16* ks       = (u16*)(ws + 13107200);
    u16* vts      = (u16*)(ws + 13369344);
    u16* qcs      = (u16*)(ws + 13631488);   // ends 13,893,632
    // reuse of dead pw1T region after L1:
    u16* k2    = (u16*)(ws + 0);
    u16* vt2   = (u16*)(ws + 262144);
    u16* sbufS = (u16*)(ws + 524288);
    u16* kcs   = (u16*)(ws + 786432);
    u16* vtcs  = (u16*)(ws + 1048576);
    u16* fo1   = (u16*)(ws + 1310720);       // 1,048,576 fl
    u16* fo2   = (u16*)(ws + 2359296);
    u16* so1   = (u16*)(ws + 3407872);
    u16* so2   = (u16*)(ws + 3670016);       // ends 3,932,160
    // d_out zf region as scratch (dead before L5 writes zf):
    u16* q2   = (u16*)(out + 0);             // 1,048,576 fl
    u16* ybuf = (u16*)(out + 1048576);       // 262,144 fl
    u16* hbuf = (u16*)(out + 1310720);       // 1,048,576 fl (= pool1 partial 0)
    u16* p1b  = (u16*)(out + 2359296);       // 1,048,576 fl (pool1 partial 1), ends 3,407,872

    // ---- cvt ----
    hipLaunchKernelGGL(c_cvt2, dim3(2560), dim3(256), 0, stream,
                       x_fast, xfb, 524288, x_slow, xsb);

    // ---- wt_all ----
    {
        WPack p; p.n = 11;
        int te = 0, i = 0;
        auto add = [&](const float* s, u16* d, int ldn, int K, int N) {
            te += (K / 64) * (N / 64);
            p.d[i++] = WDesc{s, d, ldn, K, K / 64, te};
        };
        add(pool_w1, pw1T, 2048, 4096, 2048);
        add(fself_wqkv, wqkvT_f, 1536, 512, 1536);
        add(fcross_wqkv, wqkvT_c, 1536, 512, 1536);
        add(sself_wqkv, wqkvT_s, 1536, 512, 1536);
        add(scross_wqkv, wqkvT_sc, 1536, 512, 1536);
        add(lift_w, liftT, 512, 1024, 512);
        add(pool_w2, pw2T, 512, 2048, 512);
        add(fself_wo, woT_f, 512, 512, 512);
        add(fcross_wo, woT_c, 512, 512, 512);
        add(sself_wo, woT_s, 512, 512, 512);
        add(scross_wo, woT_sc, 512, 512, 512);
        hipLaunchKernelGGL(wt_multi, dim3(te), dim3(256), 0, stream, p);
    }

    auto gl = [&](GPack& p, int i, const u16* A, int lda,
                  const u16* Bt, int ldb, const float* bias,
                  void* out0, int ldc, int M, int N, int K, int mode,
                  u16* aux0, u16* aux1, int rshift, int TM, int& te) {
        te += (M / TM) * (N / TM);
        p.d[i] = GDesc{A, Bt, bias, out0, aux0, aux1,
                       lda, ldb, ldc, K, N / TM, mode, rshift, te};
    };

    // ---- L1: input-side GEMMs; pool1 split-K=2, heavy chunks first ----
    {
        GPack p; p.n = 7; int te = 0;
        gl(p, 0, xfb, 4096, pw1T, 4096, pool_b1, hbuf, 2048,
           1024, 2048, 2048, 5, 0, 0, 0, 128, te);                    // pool1 k0
        gl(p, 1, xfb + 2048, 4096, pw1T + 2048, 4096, pool_b1, p1b, 2048,
           1024, 2048, 2048, 5, 0, 0, 0, 128, te);                    // pool1 k1
        gl(p, 2, xfb, 1024, wqkvT_f, 512, fself_bqkv, q1, 512,
           4096, 1536, 512, 3, k1, vt1, 11, 128, te);                 // fself qkv
        gl(p, 3, xfb + 512, 1024, wqkvT_c, 512, fcross_bqkv, q2, 512,
           4096, 512, 512, 1, 0, 0, 0, 128, te);                      // fcross q
        gl(p, 4, xsb, 1024, wqkvT_s, 512, sself_bqkv, qs, 512,
           1024, 1536, 512, 3, ks, vts, 9, 128, te);                  // sself qkv
        gl(p, 5, xsb, 1024, liftT, 1024, lift_b, ybuf, 512,
           1024, 512, 1024, 1, 0, 0, 0, 128, te);                     // lift
        gl(p, 6, xsb + 512, 1024, wqkvT_sc, 512, scross_bqkv, qcs, 512,
           1024, 512, 512, 1, 0, 0, 0, 128, te);                      // scross q
        hipLaunchKernelGGL(gemm_multi<8>, dim3(te), dim3(256), 0, stream, p);
    }

    // ---- gelu_sum: hbuf = gelu(hbuf + p1b + b1) ----
    hipLaunchKernelGGL(gelu_sum, dim3(1024), dim3(256), 0, stream, hbuf, p1b, pool_b1);

    // ---- L2 (64-tiles): fcross kv + pool2(shift-fused) ----
    {
        GPack p; p.n = 2; int te = 0;
        gl(p, 0, ybuf, 512, wqkvT_c + 512 * 512, 512, fcross_bqkv + 512, k2, 512,
           1024, 1024, 512, 4, 0, vt2, 9, 64, te);
        gl(p, 1, hbuf, 2048, pw2T, 2048, pool_b2, sbufS, 512,
           1024, 512, 2048, 6, 0, 0, 0, 64, te);
        hipLaunchKernelGGL(gemm_multi<4>, dim3(te), dim3(256), 0, stream, p);
    }

    // ---- L3 (64-tiles): scross kv ----
    {
        GPack p; p.n = 1; int te = 0;
        gl(p, 0, sbufS, 512, wqkvT_sc + 512 * 512, 512, scross_bqkv + 512, kcs, 512,
           1024, 1024, 512, 4, 0, vtcs, 9, 64, te);
        hipLaunchKernelGGL(gemm_multi<4>, dim3(te), dim3(256), 0, stream, p);
    }

    // ---- ATTN: all four attentions (heavy fself first) ----
    {
        APack p; p.n = 4;
        int te = 0, i = 0;
        auto add = [&](const u16* Q, const u16* K, const u16* Vt, u16* O, int Rq, int nk) {
            te += (Rq / 64) * 16;
            p.d[i++] = ADesc{Q, K, Vt, O, Rq, nk, te, 0};
        };
        add(q1, k1, vt1, fo1, 2048, 2048);   // fself
        add(q2, k2, vt2, fo2, 2048, 512);    // fcross (repeat cancels in softmax)
        add(qs, ks, vts, so1, 512, 512);     // sself
        add(qcs, kcs, vtcs, so2, 512, 512);  // scross
        hipLaunchKernelGGL(attn_multi, dim3(te), dim3(256), 0, stream, p,
                           0.125f * 1.4426950408889634f);
    }

    // ---- L5: all four out-projections (fp32 into d_out) ----
    {
        GPack p; p.n = 4; int te = 0;
        gl(p, 0, fo1, 512, woT_f, 512, fself_bo, zf, 1024,
           4096, 512, 512, 0, 0, 0, 0, 128, te);
        gl(p, 1, fo2, 512, woT_c, 512, fcross_bo, zf + 512, 1024,
           4096, 512, 512, 0, 0, 0, 0, 128, te);
        gl(p, 2, so1, 512, woT_s, 512, sself_bo, zs, 1024,
           1024, 512, 512, 0, 0, 0, 0, 128, te);
        gl(p, 3, so2, 512, woT_sc, 512, scross_bo, zs + 512, 1024,
           1024, 512, 512, 0, 0, 0, 0, 128, te);
        hipLaunchKernelGGL(gemm_multi<8>, dim3(te), dim3(256), 0, stream, p);
    }
}